// Round 1
// baseline (584.787 us; speedup 1.0000x reference)
//
#include <hip/hip_runtime.h>
#include <stdint.h>

// ---- types ----
typedef __attribute__((ext_vector_type(4))) float  f32x4a;   // MFMA acc
typedef __attribute__((ext_vector_type(8))) short  bf16x8s;  // MFMA A/B frag (8 bf16)
typedef __attribute__((ext_vector_type(8))) unsigned short u16x8;

static __device__ __forceinline__ unsigned short f2bf(float f) {
    union { float f; uint32_t u; } v; v.f = f;
    uint32_t u = v.u;
    return (unsigned short)((u + 0x7FFFu + ((u >> 16) & 1u)) >> 16);
}

// ---- x fp32 -> bf16 ----
__global__ __launch_bounds__(256) void k_cvt_bf16(const float* __restrict__ in,
                                                  unsigned short* __restrict__ out, int n8) {
    int i = blockIdx.x * blockDim.x + threadIdx.x;
    if (i >= n8) return;
    const float4* p = (const float4*)(in + (size_t)i * 8);
    float4 a = p[0], b = p[1];
    u16x8 o;
    o[0] = f2bf(a.x); o[1] = f2bf(a.y); o[2] = f2bf(a.z); o[3] = f2bf(a.w);
    o[4] = f2bf(b.x); o[5] = f2bf(b.y); o[6] = f2bf(b.z); o[7] = f2bf(b.w);
    *(u16x8*)(out + (size_t)i * 8) = o;
}

// ---- W [K][N] fp32 -> Wt [N][K] bf16 (64x64 tiles via LDS) ----
__global__ __launch_bounds__(256) void k_transpose_w(const float* __restrict__ W,
                                                     unsigned short* __restrict__ Wt,
                                                     int K, int N) {
    __shared__ float tile[64][68];
    int bx = blockIdx.x;
    int ntn = N >> 6;
    int kt = bx / ntn, nt = bx % ntn;
    int t = threadIdx.x;
    int r0 = t >> 4;            // 0..15
    int c4 = (t & 15) << 2;     // 0..60
    for (int i = 0; i < 4; ++i) {
        int k = r0 + i * 16;
        float4 v = *(const float4*)(W + (size_t)(kt * 64 + k) * N + nt * 64 + c4);
        tile[k][c4 + 0] = v.x; tile[k][c4 + 1] = v.y;
        tile[k][c4 + 2] = v.z; tile[k][c4 + 3] = v.w;
    }
    __syncthreads();
    int nl = t >> 2;            // 0..63
    int kc = (t & 3) << 4;      // 0,16,32,48
    unsigned short* dst = Wt + (size_t)(nt * 64 + nl) * K + kt * 64 + kc;
    u16x8 o0, o1;
    for (int i = 0; i < 8; ++i) o0[i] = f2bf(tile[kc + i][nl]);
    for (int i = 0; i < 8; ++i) o1[i] = f2bf(tile[kc + 8 + i][nl]);
    *(u16x8*)dst = o0;
    *(u16x8*)(dst + 8) = o1;
}

// ---- BT GEMM: C[m][n] = sum_k A[m][k]*Bt[n][k] + bias[n] ----
// 128x128 tile, BK=64, 4 waves (2x2), global_load_lds staging (m97 structure).
template<int OUT_BF16>
__global__ __launch_bounds__(256) void k_gemm_bt(const unsigned short* __restrict__ A,
                                                 const unsigned short* __restrict__ Bt,
                                                 const float* __restrict__ bias,
                                                 void* __restrict__ Cout,
                                                 int M, int N, int K, int ntn) {
    __shared__ unsigned short As[128 * 64];
    __shared__ unsigned short Bs[128 * 64];
    int bx = blockIdx.x;
    int mt = bx / ntn, nt = bx % ntn;
    int tid = threadIdx.x;
    int w = tid >> 6, lane = tid & 63;
    int wm = w >> 1, wn = w & 1;
    int l15 = lane & 15, l4 = lane >> 4;
    size_t m0 = (size_t)mt * 128, n0 = (size_t)nt * 128;

    f32x4a acc[4][4] = {};

    int srow = w * 32 + (lane >> 3);   // staged row (this lane)
    int scol = (lane & 7) * 8;         // staged k-chunk (8 bf16 = 16B)
    const unsigned short* Abase = A + (m0 + srow) * (size_t)K + scol;
    const unsigned short* Bbase = Bt + (n0 + srow) * (size_t)K + scol;

    int nkt = K >> 6;
    for (int kt = 0; kt < nkt; ++kt) {
        size_t koff = (size_t)kt * 64;
        for (int i = 0; i < 4; ++i) {
            __builtin_amdgcn_global_load_lds(
                (const __attribute__((address_space(1))) void*)(Abase + koff + (size_t)(i * 8) * K),
                (__attribute__((address_space(3))) void*)(As + (w * 32 + i * 8) * 64), 16, 0, 0);
            __builtin_amdgcn_global_load_lds(
                (const __attribute__((address_space(1))) void*)(Bbase + koff + (size_t)(i * 8) * K),
                (__attribute__((address_space(3))) void*)(Bs + (w * 32 + i * 8) * 64), 16, 0, 0);
        }
        __syncthreads();   // compiler drains vmcnt before s_barrier
        bf16x8s a[4][2], b[4][2];
        for (int mf = 0; mf < 4; ++mf)
            for (int kh = 0; kh < 2; ++kh)
                a[mf][kh] = *(const bf16x8s*)(As + (wm * 64 + mf * 16 + l15) * 64 + kh * 32 + l4 * 8);
        for (int nf = 0; nf < 4; ++nf)
            for (int kh = 0; kh < 2; ++kh)
                b[nf][kh] = *(const bf16x8s*)(Bs + (wn * 64 + nf * 16 + l15) * 64 + kh * 32 + l4 * 8);
        for (int kh = 0; kh < 2; ++kh)
            for (int mf = 0; mf < 4; ++mf)
                for (int nf = 0; nf < 4; ++nf)
                    acc[mf][nf] = __builtin_amdgcn_mfma_f32_16x16x32_bf16(a[mf][kh], b[nf][kh], acc[mf][nf], 0, 0, 0);
        __syncthreads();
    }

    for (int mf = 0; mf < 4; ++mf)
        for (int nf = 0; nf < 4; ++nf) {
            int col = (int)n0 + wn * 64 + nf * 16 + l15;
            float bv = bias[col];
            for (int r = 0; r < 4; ++r) {
                int row = (int)m0 + wm * 64 + mf * 16 + l4 * 4 + r;
                float v = acc[mf][nf][r] + bv;
                if (OUT_BF16)
                    ((unsigned short*)Cout)[(size_t)row * N + col] = f2bf(v);
                else
                    ((float*)Cout)[(size_t)row * N + col] = v;
            }
        }
}

// ---- head-wise V transpose: qkv V-part -> vt[bh][d][s] ----
__global__ __launch_bounds__(256) void k_vtrans(const unsigned short* __restrict__ qkv,
                                                unsigned short* __restrict__ vt) {
    __shared__ unsigned short tile[64][72];
    int bx = blockIdx.x;
    int bh = bx >> 5;       // 0..63
    int st = bx & 31;
    int b = bh >> 4, h = bh & 15;
    int t = threadIdx.x;
    int s0 = st * 64;
    int sl = t >> 3;        // 0..31
    int c = t & 7;          // 16B chunk
    const unsigned short* src = qkv + ((size_t)(b * 2048 + s0 + sl) * 3072) + 2048 + h * 64 + c * 8;
    *(u16x8*)&tile[sl][c * 8]      = *(const u16x8*)src;
    *(u16x8*)&tile[sl + 32][c * 8] = *(const u16x8*)(src + (size_t)32 * 3072);
    __syncthreads();
    int dl = t >> 2;        // 0..63
    int sc = (t & 3) * 16;
    u16x8 o0, o1;
    for (int i = 0; i < 8; ++i) o0[i] = tile[sc + i][dl];
    for (int i = 0; i < 8; ++i) o1[i] = tile[sc + 8 + i][dl];
    unsigned short* dst = vt + ((size_t)bh * 64 + dl) * 2048 + s0 + sc;
    *(u16x8*)dst = o0;
    *(u16x8*)(dst + 8) = o1;
}

// ---- causal flash attention: 4 waves/block, wave = 16 q-rows, 32-kv steps ----
__global__ __launch_bounds__(256) void k_attn(const unsigned short* __restrict__ qkv,
                                              const unsigned short* __restrict__ vt,
                                              unsigned short* __restrict__ ctx) {
    __shared__ unsigned short pbuf[4][16][40];   // per-wave P tile, padded (80B rows)
    int bx = blockIdx.x;
    int bh = bx >> 5;       // consecutive blocks share (b,h) -> K/V L2 reuse
    int qt = bx & 31;
    int b = bh >> 4, h = bh & 15;
    int tid = threadIdx.x;
    int w = tid >> 6, lane = tid & 63;
    int l15 = lane & 15, l4 = lane >> 4;
    int q0 = qt * 64 + w * 16;

    const unsigned short* Qb = qkv + (size_t)b * 2048 * 3072 + (size_t)h * 64;
    const unsigned short* Kb = Qb + 1024;
    const unsigned short* Vtb = vt + (size_t)bh * 64 * 2048;

    bf16x8s qf[2];
    {
        const unsigned short* p = Qb + (size_t)(q0 + l15) * 3072 + l4 * 8;
        qf[0] = *(const bf16x8s*)(p);
        qf[1] = *(const bf16x8s*)(p + 32);
    }
    f32x4a o[4] = {};
    float mrow[4], lrow[4];
    for (int r = 0; r < 4; ++r) { mrow[r] = -1e30f; lrow[r] = 0.f; }
    const float scale = 0.125f;   // 1/sqrt(64)

    int nsteps = (q0 + 16 + 31) >> 5;
    for (int s = 0; s < nsteps; ++s) {
        int kv0 = s << 5;
        f32x4a sc[2];
        for (int f = 0; f < 2; ++f) {
            const unsigned short* kp = Kb + (size_t)(kv0 + f * 16 + l15) * 3072 + l4 * 8;
            bf16x8s kf0 = *(const bf16x8s*)(kp);
            bf16x8s kf1 = *(const bf16x8s*)(kp + 32);
            f32x4a z = {0.f, 0.f, 0.f, 0.f};
            z = __builtin_amdgcn_mfma_f32_16x16x32_bf16(qf[0], kf0, z, 0, 0, 0);
            z = __builtin_amdgcn_mfma_f32_16x16x32_bf16(qf[1], kf1, z, 0, 0, 0);
            sc[f] = z;
        }
        bool need_mask = (kv0 + 31) > q0;
        float p0[4], p1[4], mloc[4];
        for (int r = 0; r < 4; ++r) {
            int qrow = q0 + l4 * 4 + r;
            float s0 = sc[0][r] * scale;
            float s1 = sc[1][r] * scale;
            if (need_mask) {
                if (kv0 + l15 > qrow)      s0 = -1e30f;
                if (kv0 + 16 + l15 > qrow) s1 = -1e30f;
            }
            p0[r] = s0; p1[r] = s1;
            mloc[r] = fmaxf(s0, s1);
        }
        for (int m = 1; m <= 8; m <<= 1)
            for (int r = 0; r < 4; ++r)
                mloc[r] = fmaxf(mloc[r], __shfl_xor(mloc[r], m));
        float alpha[4], psum[4];
        for (int r = 0; r < 4; ++r) {
            float mn = fmaxf(mrow[r], mloc[r]);
            alpha[r] = __expf(mrow[r] - mn);
            mrow[r] = mn;
            p0[r] = __expf(p0[r] - mn);
            p1[r] = __expf(p1[r] - mn);
            psum[r] = p0[r] + p1[r];
        }
        for (int m = 1; m <= 8; m <<= 1)
            for (int r = 0; r < 4; ++r)
                psum[r] += __shfl_xor(psum[r], m);
        for (int r = 0; r < 4; ++r)
            lrow[r] = lrow[r] * alpha[r] + psum[r];
        for (int nf = 0; nf < 4; ++nf)
            for (int r = 0; r < 4; ++r)
                o[nf][r] *= alpha[r];
        // P (D-layout) -> LDS -> A-fragment layout
        for (int r = 0; r < 4; ++r) {
            pbuf[w][l4 * 4 + r][l15]      = f2bf(p0[r]);
            pbuf[w][l4 * 4 + r][l15 + 16] = f2bf(p1[r]);
        }
        asm volatile("s_waitcnt lgkmcnt(0)" ::: "memory");
        bf16x8s pa = *(const bf16x8s*)(&pbuf[w][l15][l4 * 8]);
        for (int nf = 0; nf < 4; ++nf) {
            bf16x8s vf = *(const bf16x8s*)(Vtb + (size_t)(nf * 16 + l15) * 2048 + kv0 + l4 * 8);
            o[nf] = __builtin_amdgcn_mfma_f32_16x16x32_bf16(pa, vf, o[nf], 0, 0, 0);
        }
    }
    for (int nf = 0; nf < 4; ++nf) {
        int col = h * 64 + nf * 16 + l15;
        for (int r = 0; r < 4; ++r) {
            int row = q0 + l4 * 4 + r;
            float v = o[nf][r] / lrow[r];
            ctx[((size_t)b * 2048 + row) * 1024 + col] = f2bf(v);
        }
    }
}

extern "C" void kernel_launch(void* const* d_in, const int* in_sizes, int n_in,
                              void* d_out, int out_size, void* d_ws, size_t ws_size,
                              hipStream_t stream) {
    const float* x      = (const float*)d_in[0];
    const float* W_attn = (const float*)d_in[1];
    const float* b_attn = (const float*)d_in[2];
    const float* W_proj = (const float*)d_in[3];
    const float* b_proj = (const float*)d_in[4];
    float* out = (float*)d_out;

    char* ws = (char*)d_ws;
    unsigned short* xb  = (unsigned short*)ws; ws += (size_t)8192 * 1024 * 2;
    unsigned short* wta = (unsigned short*)ws; ws += (size_t)3072 * 1024 * 2;
    unsigned short* wtp = (unsigned short*)ws; ws += (size_t)1024 * 1024 * 2;
    unsigned short* qkv = (unsigned short*)ws; ws += (size_t)8192 * 3072 * 2;
    unsigned short* vt  = (unsigned short*)ws; ws += (size_t)64 * 64 * 2048 * 2;
    unsigned short* ctx = (unsigned short*)ws;

    k_cvt_bf16<<<4096, 256, 0, stream>>>(x, xb, 8192 * 1024 / 8);
    k_transpose_w<<<16 * 48, 256, 0, stream>>>(W_attn, wta, 1024, 3072);
    k_transpose_w<<<16 * 16, 256, 0, stream>>>(W_proj, wtp, 1024, 1024);
    k_gemm_bt<1><<<64 * 24, 256, 0, stream>>>(xb, wta, b_attn, (void*)qkv, 8192, 3072, 1024, 24);
    k_vtrans<<<64 * 32, 256, 0, stream>>>(qkv, vt);
    k_attn<<<64 * 32, 256, 0, stream>>>(qkv, vt, ctx);
    k_gemm_bt<0><<<64 * 8, 256, 0, stream>>>(ctx, wtp, b_proj, d_out, 8192, 1024, 1024, 8);
}

// Round 2
// 246.584 us; speedup vs baseline: 2.3716x; 2.3716x over previous
//
#include <hip/hip_runtime.h>
#include <hip/hip_bf16.h>
#include <stdint.h>

// ---- types ----
typedef __attribute__((ext_vector_type(4))) float  f32x4a;   // MFMA acc
typedef __attribute__((ext_vector_type(8))) short  bf16x8s;  // MFMA A/B frag (8 bf16)
typedef __attribute__((ext_vector_type(8))) unsigned short u16x8;

static __device__ __forceinline__ unsigned short f2bf(float f) {
    union { float f; uint32_t u; } v; v.f = f;
    uint32_t u = v.u;
    return (unsigned short)((u + 0x7FFFu + ((u >> 16) & 1u)) >> 16);
}

static __device__ __forceinline__ unsigned int pack2bf(float lo, float hi) {
    __hip_bfloat162 t = __float22bfloat162_rn(make_float2(lo, hi));  // .x -> low 16
    union { __hip_bfloat162 b; unsigned int u; } c; c.b = t;
    return c.u;
}

// ---- x fp32 -> bf16 ----
__global__ __launch_bounds__(256) void k_cvt_bf16(const float* __restrict__ in,
                                                  unsigned short* __restrict__ out, int n8) {
    int i = blockIdx.x * blockDim.x + threadIdx.x;
    if (i >= n8) return;
    const float4* p = (const float4*)(in + (size_t)i * 8);
    float4 a = p[0], b = p[1];
    u16x8 o;
    o[0] = f2bf(a.x); o[1] = f2bf(a.y); o[2] = f2bf(a.z); o[3] = f2bf(a.w);
    o[4] = f2bf(b.x); o[5] = f2bf(b.y); o[6] = f2bf(b.z); o[7] = f2bf(b.w);
    *(u16x8*)(out + (size_t)i * 8) = o;
}

// ---- W [K][N] fp32 -> Wt [N][K] bf16 (64x64 tiles via LDS) ----
__global__ __launch_bounds__(256) void k_transpose_w(const float* __restrict__ W,
                                                     unsigned short* __restrict__ Wt,
                                                     int K, int N) {
    __shared__ float tile[64][68];
    int bx = blockIdx.x;
    int ntn = N >> 6;
    int kt = bx / ntn, nt = bx % ntn;
    int t = threadIdx.x;
    int r0 = t >> 4;
    int c4 = (t & 15) << 2;
    for (int i = 0; i < 4; ++i) {
        int k = r0 + i * 16;
        float4 v = *(const float4*)(W + (size_t)(kt * 64 + k) * N + nt * 64 + c4);
        tile[k][c4 + 0] = v.x; tile[k][c4 + 1] = v.y;
        tile[k][c4 + 2] = v.z; tile[k][c4 + 3] = v.w;
    }
    __syncthreads();
    int nl = t >> 2;
    int kc = (t & 3) << 4;
    unsigned short* dst = Wt + (size_t)(nt * 64 + nl) * K + kt * 64 + kc;
    u16x8 o0, o1;
    for (int i = 0; i < 8; ++i) o0[i] = f2bf(tile[kc + i][nl]);
    for (int i = 0; i < 8; ++i) o1[i] = f2bf(tile[kc + 8 + i][nl]);
    *(u16x8*)dst = o0;
    *(u16x8*)(dst + 8) = o1;
}

// ---- BT GEMM: C[m][n] = sum_k A[m][k]*Bt[n][k] + bias[n] (m97 structure) ----
template<int OUT_BF16>
__global__ __launch_bounds__(256) void k_gemm_bt(const unsigned short* __restrict__ A,
                                                 const unsigned short* __restrict__ Bt,
                                                 const float* __restrict__ bias,
                                                 void* __restrict__ Cout,
                                                 int M, int N, int K, int ntn) {
    __shared__ unsigned short As[128 * 64];
    __shared__ unsigned short Bs[128 * 64];
    int bx = blockIdx.x;
    int mt = bx / ntn, nt = bx % ntn;
    int tid = threadIdx.x;
    int w = tid >> 6, lane = tid & 63;
    int wm = w >> 1, wn = w & 1;
    int l15 = lane & 15, l4 = lane >> 4;
    size_t m0 = (size_t)mt * 128, n0 = (size_t)nt * 128;

    f32x4a acc[4][4] = {};

    int srow = w * 32 + (lane >> 3);
    int scol = (lane & 7) * 8;
    const unsigned short* Abase = A + (m0 + srow) * (size_t)K + scol;
    const unsigned short* Bbase = Bt + (n0 + srow) * (size_t)K + scol;

    int nkt = K >> 6;
    for (int kt = 0; kt < nkt; ++kt) {
        size_t koff = (size_t)kt * 64;
        for (int i = 0; i < 4; ++i) {
            __builtin_amdgcn_global_load_lds(
                (const __attribute__((address_space(1))) void*)(Abase + koff + (size_t)(i * 8) * K),
                (__attribute__((address_space(3))) void*)(As + (w * 32 + i * 8) * 64), 16, 0, 0);
            __builtin_amdgcn_global_load_lds(
                (const __attribute__((address_space(1))) void*)(Bbase + koff + (size_t)(i * 8) * K),
                (__attribute__((address_space(3))) void*)(Bs + (w * 32 + i * 8) * 64), 16, 0, 0);
        }
        __syncthreads();
        bf16x8s a[4][2], b[4][2];
        for (int mf = 0; mf < 4; ++mf)
            for (int kh = 0; kh < 2; ++kh)
                a[mf][kh] = *(const bf16x8s*)(As + (wm * 64 + mf * 16 + l15) * 64 + kh * 32 + l4 * 8);
        for (int nf = 0; nf < 4; ++nf)
            for (int kh = 0; kh < 2; ++kh)
                b[nf][kh] = *(const bf16x8s*)(Bs + (wn * 64 + nf * 16 + l15) * 64 + kh * 32 + l4 * 8);
        for (int kh = 0; kh < 2; ++kh)
            for (int mf = 0; mf < 4; ++mf)
                for (int nf = 0; nf < 4; ++nf)
                    acc[mf][nf] = __builtin_amdgcn_mfma_f32_16x16x32_bf16(a[mf][kh], b[nf][kh], acc[mf][nf], 0, 0, 0);
        __syncthreads();
    }

    for (int mf = 0; mf < 4; ++mf)
        for (int nf = 0; nf < 4; ++nf) {
            int col = (int)n0 + wn * 64 + nf * 16 + l15;
            float bv = bias[col];
            for (int r = 0; r < 4; ++r) {
                int row = (int)m0 + wm * 64 + mf * 16 + l4 * 4 + r;
                float v = acc[mf][nf][r] + bv;
                if (OUT_BF16)
                    ((unsigned short*)Cout)[(size_t)row * N + col] = f2bf(v);
                else
                    ((float*)Cout)[(size_t)row * N + col] = v;
            }
        }
}

// ---- head-wise V transpose: qkv V-part -> vt[bh][d][s] ----
__global__ __launch_bounds__(256) void k_vtrans(const unsigned short* __restrict__ qkv,
                                                unsigned short* __restrict__ vt) {
    __shared__ unsigned short tile[64][72];
    int bx = blockIdx.x;
    int bh = bx >> 5;
    int st = bx & 31;
    int b = bh >> 4, h = bh & 15;
    int t = threadIdx.x;
    int s0 = st * 64;
    int sl = t >> 3;
    int c = t & 7;
    const unsigned short* src = qkv + ((size_t)(b * 2048 + s0 + sl) * 3072) + 2048 + h * 64 + c * 8;
    *(u16x8*)&tile[sl][c * 8]      = *(const u16x8*)src;
    *(u16x8*)&tile[sl + 32][c * 8] = *(const u16x8*)(src + (size_t)32 * 3072);
    __syncthreads();
    int dl = t >> 2;
    int sc = (t & 3) * 16;
    u16x8 o0, o1;
    for (int i = 0; i < 8; ++i) o0[i] = tile[sc + i][dl];
    for (int i = 0; i < 8; ++i) o1[i] = tile[sc + 8 + i][dl];
    unsigned short* dst = vt + ((size_t)bh * 64 + dl) * 2048 + s0 + sc;
    *(u16x8*)dst = o0;
    *(u16x8*)(dst + 8) = o1;
}

// ---- causal flash attention v2 ----
// 1024 blocks = 16 pairs x 64 bh (bx%8 == bh%8 -> XCD L2 affinity).
// Block processes 64-row q-tile j=p then j=31-p (66 kv-steps total, balanced).
// K (32x64) and V^T (64x32) staged per 32-kv step in LDS (double-buffered,
// global_load_lds w=16, XOR-swizzled source + swizzled ds_read).
// Swapped QK^T: mfma(K,Q) -> S^T, lane owns q=l15's kv values; softmax via
// in-lane tree + 2 shfl_xor; P->A-frag via 8 shfl + selects (no LDS bounce).
__global__ __launch_bounds__(256, 4) void k_attn(const unsigned short* __restrict__ qkv,
                                                 const unsigned short* __restrict__ vt,
                                                 unsigned short* __restrict__ ctx) {
    __shared__ unsigned short Ks[2][2048];   // [buf][32 rows * 64]
    __shared__ unsigned short Vs[2][2048];   // [buf][64 rows * 32]
    int bx = blockIdx.x;
    int bh = bx & 63;
    int pr = bx >> 6;                        // 0..15
    int b = bh >> 4, hd = bh & 15;
    int tid = threadIdx.x;
    int w = tid >> 6, lane = tid & 63;
    int l15 = lane & 15, l4 = lane >> 4;

    const unsigned short* Qb  = qkv + (size_t)b * 2048 * 3072 + hd * 64;
    const unsigned short* Kb  = Qb + 1024;
    const unsigned short* Vtb = vt + (size_t)bh * 64 * 2048;

    // staging source addresses (per thread), pre-swizzled (rule #21)
    int krow = tid >> 3, kc = tid & 7;       // K: 32 rows x 8 x 16B
    int vrow = tid >> 2, vc = tid & 3;       // V: 64 rows x 4 x 16B
    const unsigned short* Ksrc = Kb + (size_t)krow * 3072 + ((kc ^ (krow & 7)) << 3);
    const unsigned short* Vsrc = Vtb + (size_t)vrow * 2048 + ((vc ^ ((vrow >> 1) & 3)) << 3);

    int L0 = ((l4 & 1) << 5) + l15;          // P-redistribution source lanes
    int L1 = L0 + 16;
    bool fs = (l4 >> 1) != 0;

    for (int half = 0; half < 2; ++half) {
        int j = half ? (31 - pr) : pr;
        int q0 = j * 64 + w * 16;
        int qa = q0 + l15;                   // this lane's q row
        bf16x8s qf0, qf1;
        {
            const unsigned short* p = Qb + (size_t)(q0 + l15) * 3072 + l4 * 8;
            qf0 = *(const bf16x8s*)p;
            qf1 = *(const bf16x8s*)(p + 32);
        }
        f32x4a o[4] = {};
        float mrow = -1e30f, lrow = 0.f;
        const int NSTEPS = 2 * j + 2;

        // stage step 0
        __builtin_amdgcn_global_load_lds(
            (const __attribute__((address_space(1))) void*)Ksrc,
            (__attribute__((address_space(3))) void*)(&Ks[0][w * 512]), 16, 0, 0);
        __builtin_amdgcn_global_load_lds(
            (const __attribute__((address_space(1))) void*)Vsrc,
            (__attribute__((address_space(3))) void*)(&Vs[0][w * 512]), 16, 0, 0);
        __syncthreads();

        int s = 0;
        while (true) {
            int cur = s & 1;
            int kv0 = s << 5;
            if (s + 1 < NSTEPS) {
                int kn = (s + 1) << 5;
                __builtin_amdgcn_global_load_lds(
                    (const __attribute__((address_space(1))) void*)(Ksrc + (size_t)kn * 3072),
                    (__attribute__((address_space(3))) void*)(&Ks[cur ^ 1][w * 512]), 16, 0, 0);
                __builtin_amdgcn_global_load_lds(
                    (const __attribute__((address_space(1))) void*)(Vsrc + kn),
                    (__attribute__((address_space(3))) void*)(&Vs[cur ^ 1][w * 512]), 16, 0, 0);
            }
            const unsigned short* Kbuf = Ks[cur];
            const unsigned short* Vbuf = Vs[cur];
            // K frags (A-layout: lane row = f*16+l15, 8 d-elems at (hh*4+l4), swizzled)
            bf16x8s kf00, kf01, kf10, kf11;
            {
                int rk0 = l15, sw0 = rk0 & 7;
                kf00 = *(const bf16x8s*)(Kbuf + rk0 * 64 + (((0 + l4) ^ sw0) << 3));
                kf01 = *(const bf16x8s*)(Kbuf + rk0 * 64 + (((4 + l4) ^ sw0) << 3));
                int rk1 = 16 + l15, sw1 = rk1 & 7;
                kf10 = *(const bf16x8s*)(Kbuf + rk1 * 64 + (((0 + l4) ^ sw1) << 3));
                kf11 = *(const bf16x8s*)(Kbuf + rk1 * 64 + (((4 + l4) ^ sw1) << 3));
            }
            f32x4a z0 = {0.f, 0.f, 0.f, 0.f}, z1 = {0.f, 0.f, 0.f, 0.f};
            z0 = __builtin_amdgcn_mfma_f32_16x16x32_bf16(kf00, qf0, z0, 0, 0, 0);
            z0 = __builtin_amdgcn_mfma_f32_16x16x32_bf16(kf01, qf1, z0, 0, 0, 0);
            z1 = __builtin_amdgcn_mfma_f32_16x16x32_bf16(kf10, qf0, z1, 0, 0, 0);
            z1 = __builtin_amdgcn_mfma_f32_16x16x32_bf16(kf11, qf1, z1, 0, 0, 0);

            float p0[4], p1[4];
            bool need_mask = (kv0 + 31) > q0;
            #pragma unroll
            for (int r = 0; r < 4; ++r) {
                float s0 = z0[r] * 0.125f;
                float s1 = z1[r] * 0.125f;
                if (need_mask) {
                    if (kv0 + l4 * 4 + r > qa)      s0 = -1e30f;
                    if (kv0 + 16 + l4 * 4 + r > qa) s1 = -1e30f;
                }
                p0[r] = s0; p1[r] = s1;
            }
            float mloc = fmaxf(fmaxf(fmaxf(p0[0], p0[1]), fmaxf(p0[2], p0[3])),
                               fmaxf(fmaxf(p1[0], p1[1]), fmaxf(p1[2], p1[3])));
            mloc = fmaxf(mloc, __shfl_xor(mloc, 16));
            mloc = fmaxf(mloc, __shfl_xor(mloc, 32));
            float mn = fmaxf(mrow, mloc);
            float alpha = __expf(mrow - mn);
            mrow = mn;
            #pragma unroll
            for (int r = 0; r < 4; ++r) {
                p0[r] = __expf(p0[r] - mn);
                p1[r] = __expf(p1[r] - mn);
            }
            float psum = ((p0[0] + p0[1]) + (p0[2] + p0[3])) +
                         ((p1[0] + p1[1]) + (p1[2] + p1[3]));
            psum += __shfl_xor(psum, 16);
            psum += __shfl_xor(psum, 32);
            lrow = lrow * alpha + psum;
            // rescale O (alpha for q = l4*4+r lives in lane l4*4+r)
            #pragma unroll
            for (int r = 0; r < 4; ++r) {
                float ar = __shfl(alpha, l4 * 4 + r);
                #pragma unroll
                for (int nf = 0; nf < 4; ++nf) o[nf][r] *= ar;
            }
            // pack P to bf16 pairs and redistribute to A-fragment layout
            unsigned int pk00 = pack2bf(p0[0], p0[1]), pk01 = pack2bf(p0[2], p0[3]);
            unsigned int pk10 = pack2bf(p1[0], p1[1]), pk11 = pack2bf(p1[2], p1[3]);
            unsigned int a0 = __shfl(pk00, L0), b0 = __shfl(pk10, L0);
            unsigned int a1 = __shfl(pk01, L0), b1 = __shfl(pk11, L0);
            unsigned int a2 = __shfl(pk00, L1), b2 = __shfl(pk10, L1);
            unsigned int a3 = __shfl(pk01, L1), b3 = __shfl(pk11, L1);
            union { unsigned int u[4]; bf16x8s v; } pu;
            pu.u[0] = fs ? b0 : a0;
            pu.u[1] = fs ? b1 : a1;
            pu.u[2] = fs ? b2 : a2;
            pu.u[3] = fs ? b3 : a3;
            bf16x8s pa = pu.v;
            // PV
            #pragma unroll
            for (int nf = 0; nf < 4; ++nf) {
                int rv = nf * 16 + l15;
                bf16x8s vf = *(const bf16x8s*)(Vbuf + rv * 32 + ((l4 ^ ((rv >> 1) & 3)) << 3));
                o[nf] = __builtin_amdgcn_mfma_f32_16x16x32_bf16(pa, vf, o[nf], 0, 0, 0);
            }
            ++s;
            if (s == NSTEPS) break;
            __syncthreads();
        }
        __syncthreads();   // protect buffers before next tile restages

        float linv[4];
        #pragma unroll
        for (int r = 0; r < 4; ++r) linv[r] = 1.0f / __shfl(lrow, l4 * 4 + r);
        #pragma unroll
        for (int nf = 0; nf < 4; ++nf) {
            int col = hd * 64 + nf * 16 + l15;
            #pragma unroll
            for (int r = 0; r < 4; ++r) {
                int row = q0 + l4 * 4 + r;
                ctx[((size_t)b * 2048 + row) * 1024 + col] = f2bf(o[nf][r] * linv[r]);
            }
        }
    }
}

extern "C" void kernel_launch(void* const* d_in, const int* in_sizes, int n_in,
                              void* d_out, int out_size, void* d_ws, size_t ws_size,
                              hipStream_t stream) {
    const float* x      = (const float*)d_in[0];
    const float* W_attn = (const float*)d_in[1];
    const float* b_attn = (const float*)d_in[2];
    const float* W_proj = (const float*)d_in[3];
    const float* b_proj = (const float*)d_in[4];

    char* ws = (char*)d_ws;
    unsigned short* xb  = (unsigned short*)ws; ws += (size_t)8192 * 1024 * 2;
    unsigned short* wta = (unsigned short*)ws; ws += (size_t)3072 * 1024 * 2;
    unsigned short* wtp = (unsigned short*)ws; ws += (size_t)1024 * 1024 * 2;
    unsigned short* qkv = (unsigned short*)ws; ws += (size_t)8192 * 3072 * 2;
    unsigned short* vt  = (unsigned short*)ws; ws += (size_t)64 * 64 * 2048 * 2;
    unsigned short* ctx = (unsigned short*)ws;

    k_cvt_bf16<<<4096, 256, 0, stream>>>(x, xb, 8192 * 1024 / 8);
    k_transpose_w<<<16 * 48, 256, 0, stream>>>(W_attn, wta, 1024, 3072);
    k_transpose_w<<<16 * 16, 256, 0, stream>>>(W_proj, wtp, 1024, 1024);
    k_gemm_bt<1><<<64 * 24, 256, 0, stream>>>(xb, wta, b_attn, (void*)qkv, 8192, 3072, 1024, 24);
    k_vtrans<<<64 * 32, 256, 0, stream>>>(qkv, vt);
    k_attn<<<1024, 256, 0, stream>>>(qkv, vt, ctx);
    k_gemm_bt<0><<<64 * 8, 256, 0, stream>>>(ctx, wtp, b_proj, d_out, 8192, 1024, 1024, 8);
}

// Round 3
// 205.058 us; speedup vs baseline: 2.8518x; 1.2025x over previous
//
#include <hip/hip_runtime.h>
#include <hip/hip_bf16.h>
#include <stdint.h>

// ---- types ----
typedef __attribute__((ext_vector_type(4))) float  f32x4a;   // MFMA acc
typedef __attribute__((ext_vector_type(8))) short  bf16x8s;  // MFMA A/B frag (8 bf16)
typedef __attribute__((ext_vector_type(8))) unsigned short u16x8;

#define QSCALE 0.18033688011112042f   // 0.125 * log2(e): scores in log2 domain

static __device__ __forceinline__ unsigned short f2bf(float f) {
    union { float f; uint32_t u; } v; v.f = f;
    uint32_t u = v.u;
    return (unsigned short)((u + 0x7FFFu + ((u >> 16) & 1u)) >> 16);
}

static __device__ __forceinline__ unsigned int pack2bf(float lo, float hi) {
    __hip_bfloat162 t = __float22bfloat162_rn(make_float2(lo, hi));  // .x -> low 16
    union { __hip_bfloat162 b; unsigned int u; } c; c.b = t;
    return c.u;
}

static __device__ __forceinline__ float exp2a(float x) {
    float r;
    asm("v_exp_f32 %0, %1" : "=v"(r) : "v"(x));
    return r;
}

// ---- x fp32 -> bf16 ----
__global__ __launch_bounds__(256) void k_cvt_bf16(const float* __restrict__ in,
                                                  unsigned short* __restrict__ out, int n8) {
    int i = blockIdx.x * blockDim.x + threadIdx.x;
    if (i >= n8) return;
    const float4* p = (const float4*)(in + (size_t)i * 8);
    float4 a = p[0], b = p[1];
    u16x8 o;
    o[0] = f2bf(a.x); o[1] = f2bf(a.y); o[2] = f2bf(a.z); o[3] = f2bf(a.w);
    o[4] = f2bf(b.x); o[5] = f2bf(b.y); o[6] = f2bf(b.z); o[7] = f2bf(b.w);
    *(u16x8*)(out + (size_t)i * 8) = o;
}

// ---- bias prescale: out[i] = b[i] * (i < nscale ? sc : 1) ----
__global__ __launch_bounds__(256) void k_scale_bias(const float* __restrict__ b,
                                                    float* __restrict__ out,
                                                    int n, int nscale, float sc) {
    int i = blockIdx.x * blockDim.x + threadIdx.x;
    if (i >= n) return;
    out[i] = b[i] * (i < nscale ? sc : 1.0f);
}

// ---- W [K][N] fp32 -> Wt [N][K] bf16, cols n < nscale multiplied by sc ----
__global__ __launch_bounds__(256) void k_transpose_w(const float* __restrict__ W,
                                                     unsigned short* __restrict__ Wt,
                                                     int K, int N, float sc, int nscale) {
    __shared__ float tile[64][68];
    int bx = blockIdx.x;
    int ntn = N >> 6;
    int kt = bx / ntn, nt = bx % ntn;
    int t = threadIdx.x;
    int r0 = t >> 4;
    int c4 = (t & 15) << 2;
    for (int i = 0; i < 4; ++i) {
        int k = r0 + i * 16;
        float4 v = *(const float4*)(W + (size_t)(kt * 64 + k) * N + nt * 64 + c4);
        tile[k][c4 + 0] = v.x; tile[k][c4 + 1] = v.y;
        tile[k][c4 + 2] = v.z; tile[k][c4 + 3] = v.w;
    }
    __syncthreads();
    int nl = t >> 2;
    int kc = (t & 3) << 4;
    float s = (nt * 64 + nl < nscale) ? sc : 1.0f;
    unsigned short* dst = Wt + (size_t)(nt * 64 + nl) * K + kt * 64 + kc;
    u16x8 o0, o1;
    for (int i = 0; i < 8; ++i) o0[i] = f2bf(tile[kc + i][nl] * s);
    for (int i = 0; i < 8; ++i) o1[i] = f2bf(tile[kc + 8 + i][nl] * s);
    *(u16x8*)dst = o0;
    *(u16x8*)(dst + 8) = o1;
}

// ---- BT GEMM: C[m][n] = sum_k A[m][k]*Bt[n][k] + bias[n] (m97 structure) ----
template<int OUT_BF16>
__global__ __launch_bounds__(256) void k_gemm_bt(const unsigned short* __restrict__ A,
                                                 const unsigned short* __restrict__ Bt,
                                                 const float* __restrict__ bias,
                                                 void* __restrict__ Cout,
                                                 int M, int N, int K, int ntn) {
    __shared__ unsigned short As[128 * 64];
    __shared__ unsigned short Bs[128 * 64];
    int bx = blockIdx.x;
    int mt = bx / ntn, nt = bx % ntn;
    int tid = threadIdx.x;
    int w = tid >> 6, lane = tid & 63;
    int wm = w >> 1, wn = w & 1;
    int l15 = lane & 15, l4 = lane >> 4;
    size_t m0 = (size_t)mt * 128, n0 = (size_t)nt * 128;

    f32x4a acc[4][4] = {};

    int srow = w * 32 + (lane >> 3);
    int scol = (lane & 7) * 8;
    const unsigned short* Abase = A + (m0 + srow) * (size_t)K + scol;
    const unsigned short* Bbase = Bt + (n0 + srow) * (size_t)K + scol;

    int nkt = K >> 6;
    for (int kt = 0; kt < nkt; ++kt) {
        size_t koff = (size_t)kt * 64;
        for (int i = 0; i < 4; ++i) {
            __builtin_amdgcn_global_load_lds(
                (const __attribute__((address_space(1))) void*)(Abase + koff + (size_t)(i * 8) * K),
                (__attribute__((address_space(3))) void*)(As + (w * 32 + i * 8) * 64), 16, 0, 0);
            __builtin_amdgcn_global_load_lds(
                (const __attribute__((address_space(1))) void*)(Bbase + koff + (size_t)(i * 8) * K),
                (__attribute__((address_space(3))) void*)(Bs + (w * 32 + i * 8) * 64), 16, 0, 0);
        }
        __syncthreads();
        bf16x8s a[4][2], b[4][2];
        for (int mf = 0; mf < 4; ++mf)
            for (int kh = 0; kh < 2; ++kh)
                a[mf][kh] = *(const bf16x8s*)(As + (wm * 64 + mf * 16 + l15) * 64 + kh * 32 + l4 * 8);
        for (int nf = 0; nf < 4; ++nf)
            for (int kh = 0; kh < 2; ++kh)
                b[nf][kh] = *(const bf16x8s*)(Bs + (wn * 64 + nf * 16 + l15) * 64 + kh * 32 + l4 * 8);
        for (int kh = 0; kh < 2; ++kh)
            for (int mf = 0; mf < 4; ++mf)
                for (int nf = 0; nf < 4; ++nf)
                    acc[mf][nf] = __builtin_amdgcn_mfma_f32_16x16x32_bf16(a[mf][kh], b[nf][kh], acc[mf][nf], 0, 0, 0);
        __syncthreads();
    }

    for (int mf = 0; mf < 4; ++mf)
        for (int nf = 0; nf < 4; ++nf) {
            int col = (int)n0 + wn * 64 + nf * 16 + l15;
            float bv = bias[col];
            for (int r = 0; r < 4; ++r) {
                int row = (int)m0 + wm * 64 + mf * 16 + l4 * 4 + r;
                float v = acc[mf][nf][r] + bv;
                if (OUT_BF16)
                    ((unsigned short*)Cout)[(size_t)row * N + col] = f2bf(v);
                else
                    ((float*)Cout)[(size_t)row * N + col] = v;
            }
        }
}

// ---- head-wise V transpose: qkv V-part -> vt[bh][d][s] ----
__global__ __launch_bounds__(256) void k_vtrans(const unsigned short* __restrict__ qkv,
                                                unsigned short* __restrict__ vt) {
    __shared__ unsigned short tile[64][72];
    int bx = blockIdx.x;
    int bh = bx >> 5;
    int st = bx & 31;
    int b = bh >> 4, h = bh & 15;
    int t = threadIdx.x;
    int s0 = st * 64;
    int sl = t >> 3;
    int c = t & 7;
    const unsigned short* src = qkv + ((size_t)(b * 2048 + s0 + sl) * 3072) + 2048 + h * 64 + c * 8;
    *(u16x8*)&tile[sl][c * 8]      = *(const u16x8*)src;
    *(u16x8*)&tile[sl + 32][c * 8] = *(const u16x8*)(src + (size_t)32 * 3072);
    __syncthreads();
    int dl = t >> 2;
    int sc = (t & 3) * 16;
    u16x8 o0, o1;
    for (int i = 0; i < 8; ++i) o0[i] = tile[sc + i][dl];
    for (int i = 0; i < 8; ++i) o1[i] = tile[sc + 8 + i][dl];
    unsigned short* dst = vt + ((size_t)bh * 64 + dl) * 2048 + s0 + sc;
    *(u16x8*)dst = o0;
    *(u16x8*)(dst + 8) = o1;
}

// ---- causal flash attention v3 ----
// 1024 blocks = 16 pairs x 64 bh (bx%8 == bh%8 -> XCD L2 affinity), tiles
// j = pr then 31-pr (j+1 + 32-pr = 33 steps, balanced). KVBLK=64: K[64][64]
// and V^T[64][64] double-buffered in LDS (global_load_lds w=16, XOR-swizzled
// source + swizzled ds_read). Scores arrive in log2 domain (QSCALE folded
// into W/bias) -> raw v_exp_f32. Defer-max THR=8 (rescale ~once per tile).
// P -> A-frag via per-wave LDS bounce (padded [16][40], same-wave in-order DS).
__global__ __launch_bounds__(256, 4) void k_attn(const unsigned short* __restrict__ qkv,
                                                 const unsigned short* __restrict__ vt,
                                                 unsigned short* __restrict__ ctx) {
    __shared__ unsigned short Ks[2][64 * 64];
    __shared__ unsigned short Vs[2][64 * 64];
    __shared__ unsigned short Pb[4][16][40];
    int bx = blockIdx.x;
    int bh = bx & 63;
    int pr = bx >> 6;                        // 0..15
    int b = bh >> 4, hd = bh & 15;
    int tid = threadIdx.x;
    int w = tid >> 6, lane = tid & 63;
    int l15 = lane & 15, l4 = lane >> 4;

    const unsigned short* Qb  = qkv + (size_t)b * 2048 * 3072 + hd * 64;
    const unsigned short* Kb  = Qb + 1024;
    const unsigned short* Vtb = vt + (size_t)bh * 64 * 2048;

    // staging sources (pre-swizzled, rule #21): flat id -> row=flat>>3, chunk=flat&7
    int fl0 = tid, fl1 = tid + 256;
    int kr0 = fl0 >> 3, kc0 = fl0 & 7;
    int kr1 = fl1 >> 3, kc1 = fl1 & 7;
    const unsigned short* Ksr0 = Kb  + (size_t)kr0 * 3072 + ((kc0 ^ (kr0 & 7)) << 3);
    const unsigned short* Ksr1 = Kb  + (size_t)kr1 * 3072 + ((kc1 ^ (kr1 & 7)) << 3);
    const unsigned short* Vsr0 = Vtb + (size_t)kr0 * 2048 + ((kc0 ^ (kr0 & 7)) << 3);
    const unsigned short* Vsr1 = Vtb + (size_t)kr1 * 2048 + ((kc1 ^ (kr1 & 7)) << 3);
    unsigned short* pbw = &Pb[w][0][0];

#define STAGE(buf, kv0s)                                                                        \
    do {                                                                                        \
        size_t ko_ = (size_t)(kv0s) * 3072;                                                     \
        __builtin_amdgcn_global_load_lds(                                                       \
            (const __attribute__((address_space(1))) void*)(Ksr0 + ko_),                        \
            (__attribute__((address_space(3))) void*)(&Ks[buf][w * 512]), 16, 0, 0);            \
        __builtin_amdgcn_global_load_lds(                                                       \
            (const __attribute__((address_space(1))) void*)(Ksr1 + ko_),                        \
            (__attribute__((address_space(3))) void*)(&Ks[buf][2048 + w * 512]), 16, 0, 0);     \
        __builtin_amdgcn_global_load_lds(                                                       \
            (const __attribute__((address_space(1))) void*)(Vsr0 + (kv0s)),                     \
            (__attribute__((address_space(3))) void*)(&Vs[buf][w * 512]), 16, 0, 0);            \
        __builtin_amdgcn_global_load_lds(                                                       \
            (const __attribute__((address_space(1))) void*)(Vsr1 + (kv0s)),                     \
            (__attribute__((address_space(3))) void*)(&Vs[buf][2048 + w * 512]), 16, 0, 0);     \
    } while (0)

    for (int half = 0; half < 2; ++half) {
        int j = half ? (31 - pr) : pr;
        int q0 = j * 64 + w * 16;
        int qa = q0 + l15;
        bf16x8s qf0, qf1;
        {
            const unsigned short* p = Qb + (size_t)(q0 + l15) * 3072 + l4 * 8;
            qf0 = *(const bf16x8s*)p;
            qf1 = *(const bf16x8s*)(p + 32);
        }
        f32x4a o[4] = {};
        float mrow = 0.0f, lrow = 0.0f;
        const int NSTEPS = j + 1;

        STAGE(0, 0);
        __syncthreads();

        int s = 0;
        while (true) {
            int cur = s & 1;
            int kv0 = s << 6;
            if (s + 1 < NSTEPS) STAGE(cur ^ 1, kv0 + 64);

            const unsigned short* Kbuf = Ks[cur];
            const unsigned short* Vbuf = Vs[cur];

            // QK^T (swapped): z[f] holds S^T for kv group f*16
            f32x4a z[4];
            __builtin_amdgcn_s_setprio(1);
            #pragma unroll
            for (int f = 0; f < 4; ++f) {
                int rk = f * 16 + l15;
                int sw = rk & 7;
                bf16x8s ka = *(const bf16x8s*)(Kbuf + rk * 64 + ((l4 ^ sw) << 3));
                bf16x8s kb = *(const bf16x8s*)(Kbuf + rk * 64 + (((4 + l4) ^ sw) << 3));
                f32x4a zz = {0.f, 0.f, 0.f, 0.f};
                zz = __builtin_amdgcn_mfma_f32_16x16x32_bf16(ka, qf0, zz, 0, 0, 0);
                zz = __builtin_amdgcn_mfma_f32_16x16x32_bf16(kb, qf1, zz, 0, 0, 0);
                z[f] = zz;
            }
            __builtin_amdgcn_s_setprio(0);

            if (s == NSTEPS - 1) {   // diagonal step: causal mask
                #pragma unroll
                for (int f = 0; f < 4; ++f)
                    #pragma unroll
                    for (int r = 0; r < 4; ++r)
                        if (kv0 + f * 16 + l4 * 4 + r > qa) z[f][r] = -1e30f;
            }

            // defer-max check (log2 units, THR=8)
            float m0 = fmaxf(fmaxf(z[0][0], z[0][1]), fmaxf(z[0][2], z[0][3]));
            float m1 = fmaxf(fmaxf(z[1][0], z[1][1]), fmaxf(z[1][2], z[1][3]));
            float m2 = fmaxf(fmaxf(z[2][0], z[2][1]), fmaxf(z[2][2], z[2][3]));
            float m3 = fmaxf(fmaxf(z[3][0], z[3][1]), fmaxf(z[3][2], z[3][3]));
            float mloc = fmaxf(fmaxf(m0, m1), fmaxf(m2, m3));
            mloc = fmaxf(mloc, __shfl_xor(mloc, 16));
            mloc = fmaxf(mloc, __shfl_xor(mloc, 32));
            if (__any(mloc > mrow + 8.0f)) {
                float mn = fmaxf(mrow, mloc);
                float al = exp2a(mrow - mn);
                lrow *= al;
                #pragma unroll
                for (int r = 0; r < 4; ++r) {
                    float ar = __shfl(al, l4 * 4 + r);
                    #pragma unroll
                    for (int nf = 0; nf < 4; ++nf) o[nf][r] *= ar;
                }
                mrow = mn;
            }

            float p[4][4];
            #pragma unroll
            for (int f = 0; f < 4; ++f)
                #pragma unroll
                for (int r = 0; r < 4; ++r)
                    p[f][r] = exp2a(z[f][r] - mrow);

            float s0 = (p[0][0] + p[0][1]) + (p[0][2] + p[0][3]);
            float s1 = (p[1][0] + p[1][1]) + (p[1][2] + p[1][3]);
            float s2 = (p[2][0] + p[2][1]) + (p[2][2] + p[2][3]);
            float s3 = (p[3][0] + p[3][1]) + (p[3][2] + p[3][3]);
            float psum = (s0 + s1) + (s2 + s3);
            psum += __shfl_xor(psum, 16);
            psum += __shfl_xor(psum, 32);
            lrow += psum;

            unsigned int pk[8];
            #pragma unroll
            for (int f = 0; f < 4; ++f) {
                pk[2 * f]     = pack2bf(p[f][0], p[f][1]);
                pk[2 * f + 1] = pack2bf(p[f][2], p[f][3]);
            }

            // PV in two 32-kv halves through per-wave LDS bounce
            #pragma unroll
            for (int g = 0; g < 2; ++g) {
                *(uint2*)(pbw + l15 * 40 + l4 * 4)      = make_uint2(pk[4 * g],     pk[4 * g + 1]);
                *(uint2*)(pbw + l15 * 40 + 16 + l4 * 4) = make_uint2(pk[4 * g + 2], pk[4 * g + 3]);
                asm volatile("" ::: "memory");
                bf16x8s pa = *(const bf16x8s*)(pbw + l15 * 40 + l4 * 8);
                __builtin_amdgcn_s_setprio(1);
                #pragma unroll
                for (int nf = 0; nf < 4; ++nf) {
                    int rv = nf * 16 + l15;
                    bf16x8s vf = *(const bf16x8s*)(Vbuf + rv * 64 + (((g * 4 + l4) ^ (rv & 7)) << 3));
                    o[nf] = __builtin_amdgcn_mfma_f32_16x16x32_bf16(pa, vf, o[nf], 0, 0, 0);
                }
                __builtin_amdgcn_s_setprio(0);
                asm volatile("" ::: "memory");
            }

            ++s;
            if (s == NSTEPS) break;
            __syncthreads();
        }
        __syncthreads();   // protect buffers before next tile restages

        float linv[4];
        #pragma unroll
        for (int r = 0; r < 4; ++r) linv[r] = 1.0f / __shfl(lrow, l4 * 4 + r);
        #pragma unroll
        for (int nf = 0; nf < 4; ++nf) {
            int col = hd * 64 + nf * 16 + l15;
            #pragma unroll
            for (int r = 0; r < 4; ++r) {
                int row = q0 + l4 * 4 + r;
                ctx[((size_t)b * 2048 + row) * 1024 + col] = f2bf(o[nf][r] * linv[r]);
            }
        }
    }
#undef STAGE
}

extern "C" void kernel_launch(void* const* d_in, const int* in_sizes, int n_in,
                              void* d_out, int out_size, void* d_ws, size_t ws_size,
                              hipStream_t stream) {
    const float* x      = (const float*)d_in[0];
    const float* W_attn = (const float*)d_in[1];
    const float* b_attn = (const float*)d_in[2];
    const float* W_proj = (const float*)d_in[3];
    const float* b_proj = (const float*)d_in[4];

    char* ws = (char*)d_ws;
    unsigned short* xb  = (unsigned short*)ws; ws += (size_t)8192 * 1024 * 2;
    unsigned short* wta = (unsigned short*)ws; ws += (size_t)3072 * 1024 * 2;
    unsigned short* wtp = (unsigned short*)ws; ws += (size_t)1024 * 1024 * 2;
    unsigned short* qkv = (unsigned short*)ws; ws += (size_t)8192 * 3072 * 2;
    unsigned short* vt  = (unsigned short*)ws; ws += (size_t)64 * 64 * 2048 * 2;
    unsigned short* ctx = (unsigned short*)ws; ws += (size_t)8192 * 1024 * 2;
    float*          sbias = (float*)ws;

    k_cvt_bf16<<<4096, 256, 0, stream>>>(x, xb, 8192 * 1024 / 8);
    k_transpose_w<<<16 * 48, 256, 0, stream>>>(W_attn, wta, 1024, 3072, QSCALE, 1024);
    k_transpose_w<<<16 * 16, 256, 0, stream>>>(W_proj, wtp, 1024, 1024, 1.0f, 0);
    k_scale_bias<<<12, 256, 0, stream>>>(b_attn, sbias, 3072, 1024, QSCALE);
    k_gemm_bt<1><<<64 * 24, 256, 0, stream>>>(xb, wta, sbias, (void*)qkv, 8192, 3072, 1024, 24);
    k_vtrans<<<64 * 32, 256, 0, stream>>>(qkv, vt);
    k_attn<<<1024, 256, 0, stream>>>(qkv, vt, ctx);
    k_gemm_bt<0><<<64 * 8, 256, 0, stream>>>(ctx, wtp, b_proj, d_out, 8192, 1024, 1024, 8);
}